// Round 2
// baseline (601.009 us; speedup 1.0000x reference)
//
#include <hip/hip_runtime.h>
#include <hip/hip_bf16.h>
#include <stdint.h>

typedef __attribute__((ext_vector_type(8))) __bf16 bf16x8;
typedef __attribute__((ext_vector_type(4))) float floatx4;

#define C 128
#define BROWS 64
#define LSTR 136   // padded bf16 row stride for W: 272 B = 17*16 B -> conflict-free b128 reads

__device__ __forceinline__ __bf16 f2b(float f) {
  return __builtin_bit_cast(__bf16, __float2bfloat16(f));
}

__global__ void zero_kernel(int* __restrict__ p, int n) {
  int i = blockIdx.x * blockDim.x + threadIdx.x;
  if (i < n) p[i] = 0;
}

// histogram of row indices + W fp32 -> bf16 conversion
__global__ void prep_kernel(const int* __restrict__ rowidx, const float* __restrict__ W,
                            int* __restrict__ deg, __bf16* __restrict__ Wb, int n) {
  int i = blockIdx.x * blockDim.x + threadIdx.x;
  if (i < C * C) Wb[i] = f2b(W[i]);
  if (i < n) atomicAdd(deg + rowidx[i], 1);
}

// result[j] = (x[j] + x[col[j]]) @ W.T + 2*b + deg[j]
// Block b owns CONTIGUOUS tiles [b*tpb, b*tpb+tpb) -> sweep order preserves L3
// residency of x. Out is written with NON-TEMPORAL stores so the 256MB write
// stream neither write-allocates (RMW fetch) nor evicts x from the 256MB L3.
// A-fragments built straight from global (no sIn LDS, no per-tile barrier):
//   lane (l15, quad) owns row base+w*16+l15, k = quad*8 + kc*32 + j.
__launch_bounds__(256, 4)
__global__ void gconv_kernel(const float* __restrict__ x,
                             const int* __restrict__ colidx,
                             const __bf16* __restrict__ Wb,
                             const float* __restrict__ bias,
                             const int* __restrict__ deg,
                             float* __restrict__ out, int n, int ntiles, int tpb) {
  __shared__ __bf16 sW[C * LSTR];   // 34816 B -> 4 blocks/CU, 16 waves

  const int t = threadIdx.x;

  // ---- stage W once per block (bf16, padded rows) ----
  {
    int r = t >> 1, h = t & 1;
    const float4* src = (const float4*)(Wb + r * C + h * 64);
    float4* dst = (float4*)(sW + r * LSTR + h * 64);
#pragma unroll
    for (int i = 0; i < 8; i++) dst[i] = src[i];
  }

  const int lane = t & 63, w = t >> 6;
  const int l15 = lane & 15, quad = lane >> 4;

  // per-lane bias (col = tt*16 + l15), constant across tiles
  float b2[8];
#pragma unroll
  for (int tt = 0; tt < 8; tt++) b2[tt] = 2.0f * bias[tt * 16 + l15];

  __syncthreads();

  // B[k = quad*8 + kc*32 + j][ncol = tt*16 + l15] = W[ncol][k]
  const __bf16* bB = sW + l15 * LSTR + quad * 8;

  const int tile0 = blockIdx.x * tpb;
  const int tile1 = (tile0 + tpb < ntiles) ? tile0 + tpb : ntiles;
  if (tile0 >= ntiles) return;

  // preload first tile's row index + gather index (breaks idx->gather chain)
  int ga  = tile0 * BROWS + w * 16 + l15;
  int gal = ga < n ? ga : n - 1;
  int cg  = colidx[gal];

  for (int tile = tile0; tile < tile1; ++tile) {
    const int base = tile * BROWS + w * 16;

    // ---- issue all 16 A-side loads (256 B/lane) ----
    const float4* pa = (const float4*)(x + (size_t)gal * C + quad * 8);
    const float4* pc = (const float4*)(x + (size_t)cg  * C + quad * 8);
    float4 va[8], vc[8];
#pragma unroll
    for (int kc = 0; kc < 4; kc++) {
      va[2 * kc]     = pa[kc * 8];
      va[2 * kc + 1] = pa[kc * 8 + 1];
      vc[2 * kc]     = pc[kc * 8];
      vc[2 * kc + 1] = pc[kc * 8 + 1];
    }

    // deg for the 4 epilogue rows of this lane (row = base + quad*4 + r)
    int gr  = base + quad * 4;
    int grl = (gr + 3 < n) ? gr : ((n - 4) & ~3);
    int4 d4 = *(const int4*)(deg + grl);

    // prefetch next tile's colidx while this tile computes
    int ntile = tile + 1;
    int nga   = ntile * BROWS + w * 16 + l15;
    int ngal  = (ntile < tile1) ? (nga < n ? nga : n - 1) : gal;
    int ncg   = colidx[ngal];

    floatx4 acc[8];
#pragma unroll
    for (int i = 0; i < 8; i++) acc[i] = (floatx4){0.f, 0.f, 0.f, 0.f};

#pragma unroll
    for (int kc = 0; kc < 4; kc++) {
      float4 a0 = va[2 * kc], a1 = va[2 * kc + 1];
      float4 c0 = vc[2 * kc], c1 = vc[2 * kc + 1];
      bf16x8 av;
      av[0] = f2b(a0.x + c0.x); av[1] = f2b(a0.y + c0.y);
      av[2] = f2b(a0.z + c0.z); av[3] = f2b(a0.w + c0.w);
      av[4] = f2b(a1.x + c1.x); av[5] = f2b(a1.y + c1.y);
      av[6] = f2b(a1.z + c1.z); av[7] = f2b(a1.w + c1.w);
#pragma unroll
      for (int tt = 0; tt < 8; tt++) {
        bf16x8 bv = *(const bf16x8*)(bB + tt * 16 * LSTR + kc * 32);
        acc[tt] = __builtin_amdgcn_mfma_f32_16x16x32_bf16(av, bv, acc[tt], 0, 0, 0);
      }
    }

    // ---- epilogue: C/D layout col=l15, row=quad*4+reg (HW-verified) ----
    // Non-temporal stores: out is never re-read on device; keep it out of L2/L3.
    float dvf[4];
    dvf[0] = (float)d4.x; dvf[1] = (float)d4.y;
    dvf[2] = (float)d4.z; dvf[3] = (float)d4.w;
#pragma unroll
    for (int r = 0; r < 4; r++) {
      int g = gr + r;
      if (g < n) {
        float* orow = out + (size_t)g * C + l15;
        float dv = dvf[r];
#pragma unroll
        for (int tt = 0; tt < 8; tt++)
          __builtin_nontemporal_store(acc[tt][r] + b2[tt] + dv, orow + tt * 16);
      }
    }

    gal = ngal; cg = ncg;
  }
}

extern "C" void kernel_launch(void* const* d_in, const int* in_sizes, int n_in,
                              void* d_out, int out_size, void* d_ws, size_t ws_size,
                              hipStream_t stream) {
  const float* x    = (const float*)d_in[0];
  const int*   edge = (const int*)d_in[1];   // [2, n] flat: first n = row, next n = col
  const float* W    = (const float*)d_in[2];
  const float* bias = (const float*)d_in[3];
  float* out = (float*)d_out;

  const int n = in_sizes[0] / C;             // 500000

  int* deg = (int*)d_ws;
  size_t wb_off = ((size_t)n * sizeof(int) + 255) & ~(size_t)255;
  __bf16* Wb = (__bf16*)((char*)d_ws + wb_off);

  int nb = (n + 255) / 256;
  zero_kernel<<<nb, 256, 0, stream>>>(deg, n);
  prep_kernel<<<nb, 256, 0, stream>>>(edge, W, deg, Wb, n);

  const int ntiles = (n + BROWS - 1) / BROWS;   // 7813
  const int tpb = 4;                            // contiguous tiles per block
  const int blocks = (ntiles + tpb - 1) / tpb;  // 1954
  gconv_kernel<<<blocks, 256, 0, stream>>>(x, edge + n, Wb, bias, deg, out, n, ntiles, tpb);
}

// Round 3
// 507.127 us; speedup vs baseline: 1.1851x; 1.1851x over previous
//
#include <hip/hip_runtime.h>
#include <hip/hip_bf16.h>
#include <stdint.h>

typedef __attribute__((ext_vector_type(8))) __bf16 bf16x8;
typedef __attribute__((ext_vector_type(4))) float floatx4;

#define C 128
#define BROWS 64
#define LSTR 136   // padded bf16 row stride for W: 272 B = 17*16 B -> 2-way max on b128 reads (free)

__device__ __forceinline__ __bf16 f2b(float f) {
  return __builtin_bit_cast(__bf16, __float2bfloat16(f));
}

__global__ void zero_kernel(int* __restrict__ p, int n) {
  int i = blockIdx.x * blockDim.x + threadIdx.x;
  if (i < n) p[i] = 0;
}

// histogram of row indices + W fp32 -> bf16 conversion
__global__ void prep_kernel(const int* __restrict__ rowidx, const float* __restrict__ W,
                            int* __restrict__ deg, __bf16* __restrict__ Wb, int n) {
  int i = blockIdx.x * blockDim.x + threadIdx.x;
  if (i < C * C) Wb[i] = f2b(W[i]);
  if (i < n) atomicAdd(deg + rowidx[i], 1);
}

// result[j] = (x[j] + x[col[j]]) @ W.T + 2*b + deg[j]
// ONE TILE PER BLOCK, hardware dispatch order (this is the variable under test:
// R0's short-lived ordered blocks had FETCH=250MB/WRITE=257MB; persistent-loop
// variants R1/R2 both showed 534/400 regardless of tile ownership or store
// cache hints -> narrow ordered frontier appears to be what keeps x L3-hot).
// Kept from R1: no sIn LDS / no load-compute barrier coupling; A-fragments
// built directly from global per lane; 34.8KB LDS -> 4 blocks/CU.
__launch_bounds__(256, 4)
__global__ void gconv_kernel(const float* __restrict__ x,
                             const int* __restrict__ colidx,
                             const __bf16* __restrict__ Wb,
                             const float* __restrict__ bias,
                             const int* __restrict__ deg,
                             float* __restrict__ out, int n) {
  __shared__ __bf16 sW[C * LSTR];   // 34816 B

  const int t = threadIdx.x;
  const int lane = t & 63, w = t >> 6;
  const int l15 = lane & 15, quad = lane >> 4;

  const int base = blockIdx.x * BROWS + w * 16;

  // issue index/deg loads first -- latency hidden under W staging
  int ga  = base + l15;
  int gal = ga < n ? ga : n - 1;
  int cg  = colidx[gal];

  int gr  = base + quad * 4;
  int grl = (gr + 3 < n) ? gr : ((n - 4) & ~3);
  int4 d4 = *(const int4*)(deg + grl);

  // ---- stage W (bf16, padded rows): thread t covers row t>>1, half t&1 ----
  {
    int r = t >> 1, h = t & 1;
    const float4* src = (const float4*)(Wb + r * C + h * 64);
    float4* dst = (float4*)(sW + r * LSTR + h * 64);
#pragma unroll
    for (int i = 0; i < 8; i++) dst[i] = src[i];
  }

  // per-lane bias (col = tt*16 + l15)
  float b2[8];
#pragma unroll
  for (int tt = 0; tt < 8; tt++) b2[tt] = 2.0f * bias[tt * 16 + l15];

  __syncthreads();

  // ---- A-side: 16 float4 loads per lane, straight from global ----
  // lane (l15, quad) owns row base+l15, k = quad*8 + kc*32 + j
  const float4* pa = (const float4*)(x + (size_t)gal * C + quad * 8);
  const float4* pc = (const float4*)(x + (size_t)cg  * C + quad * 8);
  float4 va[8], vc[8];
#pragma unroll
  for (int kc = 0; kc < 4; kc++) {
    va[2 * kc]     = pa[kc * 8];
    va[2 * kc + 1] = pa[kc * 8 + 1];
    vc[2 * kc]     = pc[kc * 8];
    vc[2 * kc + 1] = pc[kc * 8 + 1];
  }

  // B[k = quad*8 + kc*32 + j][ncol = tt*16 + l15] = W[ncol][k]
  const __bf16* bB = sW + l15 * LSTR + quad * 8;

  floatx4 acc[8];
#pragma unroll
  for (int i = 0; i < 8; i++) acc[i] = (floatx4){0.f, 0.f, 0.f, 0.f};

#pragma unroll
  for (int kc = 0; kc < 4; kc++) {
    float4 a0 = va[2 * kc], a1 = va[2 * kc + 1];
    float4 c0 = vc[2 * kc], c1 = vc[2 * kc + 1];
    bf16x8 av;
    av[0] = f2b(a0.x + c0.x); av[1] = f2b(a0.y + c0.y);
    av[2] = f2b(a0.z + c0.z); av[3] = f2b(a0.w + c0.w);
    av[4] = f2b(a1.x + c1.x); av[5] = f2b(a1.y + c1.y);
    av[6] = f2b(a1.z + c1.z); av[7] = f2b(a1.w + c1.w);
#pragma unroll
    for (int tt = 0; tt < 8; tt++) {
      bf16x8 bv = *(const bf16x8*)(bB + tt * 16 * LSTR + kc * 32);
      acc[tt] = __builtin_amdgcn_mfma_f32_16x16x32_bf16(av, bv, acc[tt], 0, 0, 0);
    }
  }

  // ---- epilogue: C/D layout col=l15, row=quad*4+reg (HW-verified) ----
  float dvf[4];
  dvf[0] = (float)d4.x; dvf[1] = (float)d4.y;
  dvf[2] = (float)d4.z; dvf[3] = (float)d4.w;
#pragma unroll
  for (int r = 0; r < 4; r++) {
    int g = gr + r;
    if (g < n) {
      float* orow = out + (size_t)g * C + l15;
      float dv = dvf[r];
#pragma unroll
      for (int tt = 0; tt < 8; tt++) orow[tt * 16] = acc[tt][r] + b2[tt] + dv;
    }
  }
}

extern "C" void kernel_launch(void* const* d_in, const int* in_sizes, int n_in,
                              void* d_out, int out_size, void* d_ws, size_t ws_size,
                              hipStream_t stream) {
  const float* x    = (const float*)d_in[0];
  const int*   edge = (const int*)d_in[1];   // [2, n] flat: first n = row, next n = col
  const float* W    = (const float*)d_in[2];
  const float* bias = (const float*)d_in[3];
  float* out = (float*)d_out;

  const int n = in_sizes[0] / C;             // 500000

  int* deg = (int*)d_ws;
  size_t wb_off = ((size_t)n * sizeof(int) + 255) & ~(size_t)255;
  __bf16* Wb = (__bf16*)((char*)d_ws + wb_off);

  int nb = (n + 255) / 256;
  zero_kernel<<<nb, 256, 0, stream>>>(deg, n);
  prep_kernel<<<nb, 256, 0, stream>>>(edge, W, deg, Wb, n);

  int mb = (n + BROWS - 1) / BROWS;          // 7813 blocks, one 64-row tile each
  gconv_kernel<<<mb, 256, 0, stream>>>(x, edge + n, Wb, bias, deg, out, n);
}